// Round 9
// baseline (1072.732 us; speedup 1.0000x reference)
//
#include <hip/hip_runtime.h>
#include <hip/hip_bf16.h>

#define NB 16
#define NP 4096
#define MS 1024
#define NN 65536
#define FIN 64
#define FOUT 128
#define KNN_MARGIN 0.25f

typedef __attribute__((ext_vector_type(8))) short short8;
typedef __attribute__((ext_vector_type(4))) float f32x4;
typedef __attribute__((ext_vector_type(2))) float f32x2;

// DPP cumulative-max step (VALU pipe, no LDS)
template <int CTRL>
__device__ __forceinline__ unsigned long long dpp_max_step(unsigned long long k) {
    unsigned lo = (unsigned)k, hi = (unsigned)(k >> 32);
    unsigned plo = (unsigned)__builtin_amdgcn_update_dpp(0, (int)lo, CTRL, 0xf, 0xf, true);
    unsigned phi = (unsigned)__builtin_amdgcn_update_dpp(0, (int)hi, CTRL, 0xf, 0xf, true);
    unsigned long long pk = ((unsigned long long)phi << 32) | plo;   // invalid lanes -> 0 (identity)
    return pk > k ? pk : k;
}

__device__ __forceinline__ unsigned short bf16_rn(float v) {
    unsigned u = __float_as_uint(v);
    unsigned r = u + 0x7FFF + ((u >> 16) & 1);
    return (unsigned short)(r >> 16);
}

// ---------------------------------------------------------------- front: FPS + GEMM + xnorm/split fused
__global__ __launch_bounds__(512, 1) void front_kernel(
        const float* __restrict__ pos, const float* __restrict__ feat,
        const float* __restrict__ W, const float* __restrict__ bias,
        int* __restrict__ fps_idx, float* __restrict__ out_pos, float* __restrict__ out_batch,
        float* __restrict__ xnorm, unsigned short* __restrict__ Xhi, unsigned short* __restrict__ Xlo,
        __hip_bfloat16* __restrict__ hout, float* __restrict__ gsum, float* __restrict__ gsq) {
    __shared__ float smem[13344];
    const int t = threadIdx.x;
    const int b = blockIdx.x;
    if (b < 16) {
        // ---------------- FPS: 512 threads x 8 pts/thread; packed-f32 phase A
        // pairs (j, j+4) share a f32x2 lane -> identical values/pairing as the scalar
        // version (v_pk_add/v_pk_fma are IEEE-identical), so selected indices are unchanged.
        float* plds = smem;                                   // 12288 floats
        int* idxL = (int*)(smem + 12288);                     // 1024 ints
        unsigned long long* rk = (unsigned long long*)(smem + 13312);  // 16 u64
        const float* pb = pos + (size_t)b * NP * 3;
#pragma unroll
        for (int i = 0; i < 24; i++) { int id = t + 512 * i; plds[id] = pb[id]; }
        __syncthreads();
        f32x2 px2[4], py2[4], pz2[4], dist2[4];
#pragma unroll
        for (int j = 0; j < 4; j++) {
            int pA = t + 512 * j, pB = t + 512 * (j + 4);
            px2[j] = (f32x2){plds[pA * 3 + 0], plds[pB * 3 + 0]};
            py2[j] = (f32x2){plds[pA * 3 + 1], plds[pB * 3 + 1]};
            pz2[j] = (f32x2){plds[pA * 3 + 2], plds[pB * 3 + 2]};
            dist2[j] = (f32x2){INFINITY, INFINITY};
        }
        float lx = plds[0], ly = plds[1], lz = plds[2];
        if (t == 0) idxL[0] = 0;
        const int ln = t & 63, wv = t >> 6;   // 8 waves
        for (int m = 1; m < MS; m++) {
            f32x2 l2x = {lx, lx}, l2y = {ly, ly}, l2z = {lz, lz};
#pragma unroll
            for (int j = 0; j < 4; j++) {
                f32x2 dx = px2[j] - l2x, dy = py2[j] - l2y, dz = pz2[j] - l2z;
                f32x2 d = __builtin_elementwise_fma(dx, dx,
                              __builtin_elementwise_fma(dy, dy, dz * dz));
                dist2[j] = __builtin_elementwise_min(dist2[j], d);
            }
            // in-thread argmax: level 1 = within-vector pair (j, j+4), then tree over 4
            float d1[4]; int i1[4];
#pragma unroll
            for (int j = 0; j < 4; j++) {
                bool g = dist2[j].y > dist2[j].x;
                d1[j] = g ? dist2[j].y : dist2[j].x; i1[j] = g ? (j + 4) : j;
            }
            float d2[2]; int i2[2];
#pragma unroll
            for (int i = 0; i < 2; i++) {
                bool g = d1[i + 2] > d1[i];
                d2[i] = g ? d1[i + 2] : d1[i]; i2[i] = g ? i1[i + 2] : i1[i];
            }
            bool g3 = d2[1] > d2[0];
            float bd = g3 ? d2[1] : d2[0];
            int bi = g3 ? i2[1] : i2[0];
            int bp = t + (bi << 9);
            unsigned long long key =
                ((unsigned long long)__float_as_uint(bd) << 32) | (unsigned)(~bp);
            key = dpp_max_step<0x111>(key);   // row_shr:1
            key = dpp_max_step<0x112>(key);   // row_shr:2
            key = dpp_max_step<0x114>(key);   // row_shr:4
            key = dpp_max_step<0x118>(key);   // row_shr:8
            key = dpp_max_step<0x142>(key);   // row_bcast15
            key = dpp_max_step<0x143>(key);   // row_bcast31
            const int par = (m & 1) * 8;
            if (ln == 63) rk[par + wv] = key;
            __syncthreads();
            unsigned long long k0 = rk[par + 0], k1 = rk[par + 1];
            unsigned long long k2 = rk[par + 2], k3 = rk[par + 3];
            unsigned long long k4 = rk[par + 4], k5 = rk[par + 5];
            unsigned long long k6 = rk[par + 6], k7 = rk[par + 7];
            unsigned long long ka = k0 > k1 ? k0 : k1;
            unsigned long long kb = k2 > k3 ? k2 : k3;
            unsigned long long kc = k4 > k5 ? k4 : k5;
            unsigned long long kd = k6 > k7 ? k6 : k7;
            ka = ka > kb ? ka : kb;
            kc = kc > kd ? kc : kd;
            unsigned long long kw = ka > kc ? ka : kc;
            bp = (int)(~(unsigned)kw) & 0xFFF;
            lx = plds[bp * 3 + 0]; ly = plds[bp * 3 + 1]; lz = plds[bp * 3 + 2];
            if (t == 0) idxL[m] = bp;
        }
        __syncthreads();
        for (int m = t; m < MS; m += 512) {
            int ix = idxL[m];
            size_t o = (size_t)b * MS + m;
            fps_idx[o] = ix;
            out_pos[o * 3 + 0] = plds[ix * 3 + 0];
            out_pos[o * 3 + 1] = plds[ix * 3 + 1];
            out_pos[o * 3 + 2] = plds[ix * 3 + 2];
            out_batch[o] = (float)b;
        }
    } else if (b < 272) {
        // ---------------- GEMM + BN stats (rows (b-16)*256 .. +255), 512 threads
        float* wt = smem;            // [128][68] W^T
        float* fl = smem + 8704;     // [64][68] feature tile
#pragma unroll
        for (int it = 0; it < 4; it++) {
            int lid = t + 512 * it;
            int k = lid >> 5, c4 = lid & 31;
            float4 v = *(const float4*)&W[k * FOUT + c4 * 4];
            wt[(c4 * 4 + 0) * 68 + k] = v.x;
            wt[(c4 * 4 + 1) * 68 + k] = v.y;
            wt[(c4 * 4 + 2) * 68 + k] = v.z;
            wt[(c4 * 4 + 3) * 68 + k] = v.w;
        }
        const int rowbase0 = (b - 16) * 256;
        const int rg = t >> 5, cg = t & 31;
        float sums[4] = {0, 0, 0, 0};
        float sqs[4]  = {0, 0, 0, 0};
        for (int sub = 0; sub < 4; sub++) {
            const int rowbase = rowbase0 + sub * 64;
            __syncthreads();
#pragma unroll
            for (int it = 0; it < 2; it++) {
                int lid = t + 512 * it;
                int r = lid >> 4, f4 = lid & 15;
                float4 v = *(const float4*)&feat[(size_t)(rowbase + r) * FIN + f4 * 4];
                *(float4*)&fl[r * 68 + f4 * 4] = v;
            }
            __syncthreads();
            float acc[4][4];
#pragma unroll
            for (int i = 0; i < 4; i++)
#pragma unroll
                for (int j = 0; j < 4; j++) acc[i][j] = 0.f;
#pragma unroll 2
            for (int k4 = 0; k4 < 16; k4++) {
                float4 f4v[4], w4v[4];
#pragma unroll
                for (int i = 0; i < 4; i++) f4v[i] = *(float4*)&fl[(rg * 4 + i) * 68 + k4 * 4];
#pragma unroll
                for (int j = 0; j < 4; j++) w4v[j] = *(float4*)&wt[(cg + 32 * j) * 68 + k4 * 4];
#pragma unroll
                for (int i = 0; i < 4; i++)
#pragma unroll
                    for (int j = 0; j < 4; j++) {
                        acc[i][j] = fmaf(f4v[i].x, w4v[j].x, acc[i][j]);
                        acc[i][j] = fmaf(f4v[i].y, w4v[j].y, acc[i][j]);
                        acc[i][j] = fmaf(f4v[i].z, w4v[j].z, acc[i][j]);
                        acc[i][j] = fmaf(f4v[i].w, w4v[j].w, acc[i][j]);
                    }
            }
#pragma unroll
            for (int j = 0; j < 4; j++) {
                int c = cg + 32 * j;
                float bc = bias[c];
#pragma unroll
                for (int i = 0; i < 4; i++) {
                    float h = acc[i][j] + bc;
                    sums[j] += h; sqs[j] += h * h;
                    hout[(size_t)(rowbase + rg * 4 + i) * FOUT + c] = __float2bfloat16(h);
                }
            }
        }
        __syncthreads();
        float* suml = fl;
        float* sql  = wt;
#pragma unroll
        for (int j = 0; j < 4; j++) {
            suml[rg * FOUT + cg + 32 * j] = sums[j];
            sql[rg * FOUT + cg + 32 * j]  = sqs[j];
        }
        __syncthreads();
        if (t < FOUT) {
            float S = 0.f, Q = 0.f;
#pragma unroll
            for (int r = 0; r < 16; r++) { S += suml[r * FOUT + t]; Q += sql[r * FOUT + t]; }
            atomicAdd(&gsum[t], S);
            atomicAdd(&gsq[t], Q);
        }
    } else {
        // ---------------- xnorm + bf16 hi/lo split (512 threads, 128 blocks)
        int r = (b - 272) * 512 + t;
        const float4* fr = (const float4*)&feat[(size_t)r * FIN];
        unsigned short hrow[64], lrow[64];
        float s = 0.f;
#pragma unroll
        for (int i = 0; i < 16; i++) {
            float4 v = fr[i];
            s += v.x * v.x + v.y * v.y + v.z * v.z + v.w * v.w;
            float vv[4] = {v.x, v.y, v.z, v.w};
#pragma unroll
            for (int j = 0; j < 4; j++) {
                unsigned short h = bf16_rn(vv[j]);
                float hf = __uint_as_float((unsigned)h << 16);
                hrow[4 * i + j] = h;
                lrow[4 * i + j] = bf16_rn(vv[j] - hf);
            }
        }
        xnorm[r] = s;
#pragma unroll
        for (int i = 0; i < 8; i++) {
            short8 hv, lv;
#pragma unroll
            for (int j = 0; j < 8; j++) { hv[j] = (short)hrow[8 * i + j]; lv[j] = (short)lrow[8 * i + j]; }
            *(short8*)&Xhi[(size_t)r * 64 + 8 * i] = hv;
            *(short8*)&Xlo[(size_t)r * 64 + 8 * i] = lv;
        }
    }
}

// ---------------------------------------------------------------- BN finalize
__global__ void finalize_kernel(const float* __restrict__ gsum, const float* __restrict__ gsq,
        const float* __restrict__ gamma, const float* __restrict__ beta,
        float* __restrict__ acoef, float* __restrict__ ccoef) {
    int c = threadIdx.x;
    float mean = gsum[c] * (1.0f / NN);
    float var  = gsq[c] * (1.0f / NN) - mean * mean;
    float s = rsqrtf(var + 1e-5f) * gamma[c];
    acoef[c] = s;
    ccoef[c] = beta[c] - mean * s;
}

// ---------------------------------------------------------------- KNN filter: MFMA + two-phase threshold
// (unchanged from R8 — validated). grid 512: cloud(16) x qgroup(16) x half(2).
__global__ __launch_bounds__(256, 2) void knn_kernel(
        const unsigned short* __restrict__ Xhi, const unsigned short* __restrict__ Xlo,
        const int* __restrict__ fps_idx, const float* __restrict__ xnorm,
        unsigned short* __restrict__ cand) {
    __shared__ float TL[4][16][32];
    __shared__ float TQ[4][16];
    __shared__ int   cntL[4][16];
    __shared__ unsigned short buf[4][16][64];
    const int t = threadIdx.x, b = blockIdx.x;
    const int cloud = b & 15, qg = (b >> 4) & 15, half = b >> 8;
    const int wave = t >> 6, lane = t & 63;
    const int quad = lane >> 4, col = lane & 15;
    const int cbase = cloud * NP;
    const int qloc = qg * 64 + wave * 16;

    const int qrow = fps_idx[cloud * MS + qloc + col];
    const unsigned short* Qh = Xhi + (size_t)(cbase + qrow) * 64;
    const unsigned short* Ql = Xlo + (size_t)(cbase + qrow) * 64;
    short8 Ah0 = *(const short8*)(Qh + quad * 8);
    short8 Ah1 = *(const short8*)(Qh + 32 + quad * 8);
    short8 Al0 = *(const short8*)(Ql + quad * 8);
    short8 Al1 = *(const short8*)(Ql + 32 + quad * 8);

    const int pstart = half * 2048;
    float mA[4] = {INFINITY, INFINITY, INFINITY, INFINITY};
    float mB[4] = {INFINITY, INFINITY, INFINITY, INFINITY};
    for (int tile = 0; tile < 128; tile++) {
        const int prow = cbase + pstart + tile * 16 + col;
        const unsigned short* Bh = Xhi + (size_t)prow * 64;
        const unsigned short* Bl = Xlo + (size_t)prow * 64;
        short8 bh0 = *(const short8*)(Bh + quad * 8);
        short8 bh1 = *(const short8*)(Bh + 32 + quad * 8);
        short8 bl0 = *(const short8*)(Bl + quad * 8);
        short8 bl1 = *(const short8*)(Bl + 32 + quad * 8);
        f32x4 acc = {0.f, 0.f, 0.f, 0.f};
        acc = __builtin_amdgcn_mfma_f32_16x16x32_bf16(Ah0, bh0, acc, 0, 0, 0);
        acc = __builtin_amdgcn_mfma_f32_16x16x32_bf16(Ah1, bh1, acc, 0, 0, 0);
        acc = __builtin_amdgcn_mfma_f32_16x16x32_bf16(Al0, bh0, acc, 0, 0, 0);
        acc = __builtin_amdgcn_mfma_f32_16x16x32_bf16(Al1, bh1, acc, 0, 0, 0);
        acc = __builtin_amdgcn_mfma_f32_16x16x32_bf16(Ah0, bl0, acc, 0, 0, 0);
        acc = __builtin_amdgcn_mfma_f32_16x16x32_bf16(Ah1, bl1, acc, 0, 0, 0);
        float xnv = xnorm[prow];
#pragma unroll
        for (int r = 0; r < 4; r++) {
            float s = fmaf(-2.0f, acc[r], xnv);
            float mx = fmaxf(mA[r], s);
            mA[r] = fminf(mA[r], s);
            mB[r] = fminf(mB[r], mx);
        }
    }
#pragma unroll
    for (int r = 0; r < 4; r++) {
        TL[wave][quad * 4 + r][col * 2 + 0] = mA[r];
        TL[wave][quad * 4 + r][col * 2 + 1] = mB[r];
    }
    if (lane < 16) cntL[wave][lane] = 0;
    {
        const int q = lane >> 2, j0 = (lane & 3) * 8;
        float v[32];
#pragma unroll
        for (int j = 0; j < 32; j++) v[j] = TL[wave][q][j];
#pragma unroll
        for (int u = 0; u < 8; u++) {
            float vj = TL[wave][q][j0 + u];
            int jj = j0 + u, rank = 0;
#pragma unroll
            for (int k = 0; k < 32; k++)
                rank += (v[k] < vj || (v[k] == vj && k < jj)) ? 1 : 0;
            if (rank == 15) TQ[wave][q] = vj;
        }
    }
    float T0 = TQ[wave][quad * 4 + 0] + KNN_MARGIN;
    float T1 = TQ[wave][quad * 4 + 1] + KNN_MARGIN;
    float T2 = TQ[wave][quad * 4 + 2] + KNN_MARGIN;
    float T3 = TQ[wave][quad * 4 + 3] + KNN_MARGIN;
    for (int tile = 0; tile < 128; tile++) {
        const int pidx = pstart + tile * 16 + col;
        const int prow = cbase + pidx;
        const unsigned short* Bh = Xhi + (size_t)prow * 64;
        const unsigned short* Bl = Xlo + (size_t)prow * 64;
        short8 bh0 = *(const short8*)(Bh + quad * 8);
        short8 bh1 = *(const short8*)(Bh + 32 + quad * 8);
        short8 bl0 = *(const short8*)(Bl + quad * 8);
        short8 bl1 = *(const short8*)(Bl + 32 + quad * 8);
        f32x4 acc = {0.f, 0.f, 0.f, 0.f};
        acc = __builtin_amdgcn_mfma_f32_16x16x32_bf16(Ah0, bh0, acc, 0, 0, 0);
        acc = __builtin_amdgcn_mfma_f32_16x16x32_bf16(Ah1, bh1, acc, 0, 0, 0);
        acc = __builtin_amdgcn_mfma_f32_16x16x32_bf16(Al0, bh0, acc, 0, 0, 0);
        acc = __builtin_amdgcn_mfma_f32_16x16x32_bf16(Al1, bh1, acc, 0, 0, 0);
        acc = __builtin_amdgcn_mfma_f32_16x16x32_bf16(Ah0, bl0, acc, 0, 0, 0);
        acc = __builtin_amdgcn_mfma_f32_16x16x32_bf16(Ah1, bl1, acc, 0, 0, 0);
        float xnv = xnorm[prow];
        float s0 = fmaf(-2.0f, acc[0], xnv);
        float s1 = fmaf(-2.0f, acc[1], xnv);
        float s2 = fmaf(-2.0f, acc[2], xnv);
        float s3 = fmaf(-2.0f, acc[3], xnv);
        if (s0 <= T0) { int p = atomicAdd(&cntL[wave][quad * 4 + 0], 1); if (p < 64) buf[wave][quad * 4 + 0][p] = (unsigned short)pidx; }
        if (s1 <= T1) { int p = atomicAdd(&cntL[wave][quad * 4 + 1], 1); if (p < 64) buf[wave][quad * 4 + 1][p] = (unsigned short)pidx; }
        if (s2 <= T2) { int p = atomicAdd(&cntL[wave][quad * 4 + 2], 1); if (p < 64) buf[wave][quad * 4 + 2][p] = (unsigned short)pidx; }
        if (s3 <= T3) { int p = atomicAdd(&cntL[wave][quad * 4 + 3], 1); if (p < 64) buf[wave][quad * 4 + 3][p] = (unsigned short)pidx; }
    }
#pragma unroll
    for (int q = 0; q < 16; q++) {
        int n = cntL[wave][q];
        unsigned short val = (lane < n) ? buf[wave][q][lane] : (unsigned short)0xFFFF;
        cand[(size_t)(cloud * MS + qloc + q) * 128 + half * 64 + lane] = val;
    }
}

// ---------------------------------------------------------------- refine: exact fp32 top-16 + gather/BN/ReLU/maxpool
// BATCHED: block = 8 queries (grid 2048) to amortize per-block dispatch/setup cost.
__global__ __launch_bounds__(256) void refine_kernel(
        const float* __restrict__ feat, const int* __restrict__ fps_idx,
        const float* __restrict__ xnorm, const unsigned short* __restrict__ cand,
        const __hip_bfloat16* __restrict__ h, const float* __restrict__ acoef,
        const float* __restrict__ ccoef, float* __restrict__ out_feat) {
    __shared__ float qlds[64];
    __shared__ float cD[128];
    __shared__ int   cI[128];
    __shared__ int   fIdx[16];
    __shared__ float cf[256];
    const int t = threadIdx.x, b = blockIdx.x;
    const int cloud = b & 15, qoct = b >> 4;       // cloud <-> XCD locality; qoct 0..127
    const int cbase = cloud * NP;
    if (t < 128) cf[t] = acoef[t]; else cf[t] = ccoef[t - 128];
    const __hip_bfloat16* hb = h + (size_t)cbase * FOUT;

    for (int qi = 0; qi < 8; qi++) {
        const int q = cloud * MS + qoct * 8 + qi;
        if (t < 16) {
            int qr = fps_idx[q];
            float4 v = ((const float4*)(feat + (size_t)(cbase + qr) * FIN))[t];
            *(float4*)&qlds[t * 4] = v;
        }
        __syncthreads();
        // exact fp32 distance: candidate c = t>>1, half jh = t&1 covers 32 dims
        const int c = t >> 1, jh = t & 1;
        const unsigned short cs = cand[(size_t)q * 128 + c];
        const bool valid = (cs != 0xFFFF);
        const int cidx = valid ? (int)cs : 0;
        const float4* xr = (const float4*)(feat + (size_t)(cbase + cidx) * FIN) + jh * 8;
        float a0 = 0.f, a1 = 0.f, a2 = 0.f, a3 = 0.f;
#pragma unroll
        for (int i = 0; i < 8; i++) {
            float4 x4 = xr[i];
            a0 = fmaf(qlds[jh * 32 + 4 * i + 0], x4.x, a0);
            a1 = fmaf(qlds[jh * 32 + 4 * i + 1], x4.y, a1);
            a2 = fmaf(qlds[jh * 32 + 4 * i + 2], x4.z, a2);
            a3 = fmaf(qlds[jh * 32 + 4 * i + 3], x4.w, a3);
        }
        float a = (a0 + a1) + (a2 + a3);
        a += __shfl_xor(a, 1);
        if (jh == 0) {
            cD[c] = valid ? fmaf(-2.0f, a, xnorm[cbase + cidx]) : INFINITY;
            cI[c] = valid ? cidx : (65536 + c);   // distinct tiebreak ids for sentinels
        }
        __syncthreads();
        // rank-count among 128 (lex (d, idx); >=32 real distinct candidates guaranteed)
        if (t < 128) {
            float dv = cD[t]; int iv = cI[t]; int rank = 0;
#pragma unroll 8
            for (int j = 0; j < 128; j++) {
                float dj = cD[j]; int ij = cI[j];
                rank += (dj < dv || (dj == dv && ij < iv)) ? 1 : 0;
            }
            if (rank < 16) fIdx[rank] = iv;
        }
        __syncthreads();
        // gather + BN affine + relu + maxpool
        if (t < 128) {
            const float ac = cf[t], cc = cf[128 + t];
            float mx = -INFINITY;
#pragma unroll
            for (int k = 0; k < 16; k++) {
                int row = fIdx[k];
                float hv = __bfloat162float(hb[(size_t)row * FOUT + t]);
                mx = fmaxf(mx, fmaxf(fmaf(ac, hv, cc), 0.f));
            }
            out_feat[(size_t)q * FOUT + t] = mx;
        }
        __syncthreads();
    }
}

// ---------------------------------------------------------------- launch
extern "C" void kernel_launch(void* const* d_in, const int* in_sizes, int n_in,
                              void* d_out, int out_size, void* d_ws, size_t ws_size,
                              hipStream_t stream) {
    (void)in_sizes; (void)n_in; (void)out_size; (void)ws_size;
    const float* position = (const float*)d_in[0];
    const float* features = (const float*)d_in[1];
    const float* W        = (const float*)d_in[3];
    const float* bias     = (const float*)d_in[4];
    const float* gamma    = (const float*)d_in[5];
    const float* beta     = (const float*)d_in[6];
    float* out = (float*)d_out;

    char* ws = (char*)d_ws;
    int*   fps_idx = (int*)ws;                               // 64 KB
    float* gsum    = (float*)(ws + 65536);                   // 512 B
    float* gsq     = (float*)(ws + 66048);                   // 512 B
    float* acoef   = (float*)(ws + 66560);                   // 512 B
    float* ccoef   = (float*)(ws + 67072);                   // 512 B
    float* xnorm   = (float*)(ws + 67584);                   // 256 KB -> ends 329728
    unsigned short* cand = (unsigned short*)(ws + 329728);   // 4 MB   -> ends 4524032
    unsigned short* Xhi  = (unsigned short*)(ws + 4524032);  // 8 MB   -> ends 12912640
    __hip_bfloat16* hbuf = (__hip_bfloat16*)(ws + 12912640); // 16 MB  -> ends ~29.7 MB

    float* out_feat  = out;                 // [16384][128]
    float* out_pos   = out + 2097152;       // [16384][3]
    float* out_batch = out + 2146304;       // [16384]
    // Stash Xlo in the out_feat region (8 MB exact fit); refine overwrites it afterwards.
    unsigned short* Xlo = (unsigned short*)out;

    hipMemsetAsync(gsum, 0, 1024, stream);  // zero gsum+gsq
    front_kernel<<<400, 512, 0, stream>>>(position, features, W, bias,
                                          fps_idx, out_pos, out_batch, xnorm, Xhi, Xlo,
                                          hbuf, gsum, gsq);
    finalize_kernel<<<1, FOUT, 0, stream>>>(gsum, gsq, gamma, beta, acoef, ccoef);
    knn_kernel<<<512, 256, 0, stream>>>(Xhi, Xlo, fps_idx, xnorm, cand);
    refine_kernel<<<2048, 256, 0, stream>>>(features, fps_idx, xnorm, cand,
                                            hbuf, acoef, ccoef, out_feat);
}